// Round 12
// baseline (6328.453 us; speedup 1.0000x reference)
//
#include <hip/hip_runtime.h>

#define B_TOT   512
#define T_LEN   512
#define F_IN_D  8
#define H_DIM   128
#define OUT_DIM 7
#define TC      8                 // timesteps per chunk
#define NCHUNK  (T_LEN / TC)      // 64
#define RSLOT   16                // ring slots per layer boundary
#define BBATCH  16                // batch rows per group (full MFMA N)
#define NGRP    (B_TOT / BBATCH)  // 32 groups
#define NTHREADS 1024             // 16 waves = 2 groups x 8 waves
#define SPIN_LIMIT (1 << 18)      // bounded waits: fail-visible, never hang

typedef __bf16 bf16x8 __attribute__((ext_vector_type(8)));
typedef __bf16 bf16x4 __attribute__((ext_vector_type(4)));
typedef float  f32x4  __attribute__((ext_vector_type(4)));
typedef unsigned long long u64;

// ---- workspace layout (bf16 element offsets) ----
#define WS_WHH   0                     // [3][32][4][64][8] = 196608
#define WS_WIH12 196608                // [2][32][4][64][8] = 131072
#define WS_WIH0  327680                // [32][64][8] = 16384 (k>=8 zero-padded)
#define WS_BIAS  344064                // float[3][512] combined b_ih+b_hh
#define WS_FLAGS 347136                // int[2][32] flags, then int[2][32] consumed
#define WS_BUF   347648                // [2][32] pair ring buffers
#define CH_ELEMS   (TC * BBATCH * H_DIM)   // 16384 bf16 per chunk (32 KB)
#define CH_U64     (CH_ELEMS / 4)          // 4096 u64 per chunk
#define PAIR_ELEMS (RSLOT * CH_ELEMS)      // 262144 (512 KiB per pair)

// hist layout [s][kgroup][batch][8]: h(t=c*TC+s) element (b, k) at
// [s][k>>3][b][k&7]. Step s reads its B-frag from hist[s-1] (s=0: hist[TC-1],
// the previous chunk's tail -- valid: flush reads complete at phase C, new
// writes happen after) -> the separate h[2] buffer is GONE (one ds_write per
// step). Reads are contiguous 1KB wave reads, zero bank conflicts. Ring slots
// use the same layout: flush is a verbatim 32KB copy.
struct __align__(16) SharedMem {
  __bf16 hist[2][TC][16][16][8];  // [grp][s][kgroup][batch][k&7]  2x32 KB
  u64    ring[2][CH_U64];         // [grp] LDS mirror of upstream   2x32 KB
};                                // 128 KB; z (FC head) aliases ring

__device__ __forceinline__ float sigf(float x) {
  return __builtin_amdgcn_rcpf(1.f + __expf(-x));
}
// sig(a) * tanh(x) with ONE rcp: (E-1) / ((1+e^-a)(E+1)), E = e^{2*clamp(x)}.
__device__ __forceinline__ float sigmul(float a, float x) {
  const float xc = fminf(fmaxf(x, -15.f), 15.f);
  const float E  = __expf(2.f * xc);
  const float F  = __expf(-a);
  return (E - 1.f) * __builtin_amdgcn_rcpf((1.f + F) * (E + 1.f));
}
__device__ __forceinline__ bf16x8 load8_f32_bf16(const float* p) {
  const f32x4 a = *(const f32x4*)p;
  const f32x4 b = *(const f32x4*)(p + 4);
  bf16x8 r;
  #pragma unroll
  for (int j = 0; j < 4; ++j) { r[j] = (__bf16)a[j]; r[4 + j] = (__bf16)b[j]; }
  return r;
}
__device__ __forceinline__ bf16x8 zero_bf16x8() {
  bf16x8 r;
  #pragma unroll
  for (int j = 0; j < 8; ++j) r[j] = (__bf16)0.f;
  return r;
}
// All cross-block traffic is agent-scope RELAXED atomics -> coherent at the
// IC by construction (no wbl2/inv cache maintenance; R6 measured win).
// Ordering: the phase-C __syncthreads drains each thread's vmcnt(0)
// (compiler-guaranteed before s_barrier), so data atomics are complete at the
// coherence point before any flag atomic issued after it.
__device__ __forceinline__ int afl_load(int* p) {
  return __hip_atomic_load(p, __ATOMIC_RELAXED, __HIP_MEMORY_SCOPE_AGENT);
}
__device__ __forceinline__ void afl_store(int* p, int v) {
  __hip_atomic_store(p, v, __ATOMIC_RELAXED, __HIP_MEMORY_SCOPE_AGENT);
}
__device__ __forceinline__ u64 adat_load(const u64* p) {
  return __hip_atomic_load(p, __ATOMIC_RELAXED, __HIP_MEMORY_SCOPE_AGENT);
}
__device__ __forceinline__ void adat_store(u64* p, u64 v) {
  __hip_atomic_store(p, v, __ATOMIC_RELAXED, __HIP_MEMORY_SCOPE_AGENT);
}
// Bounded poll (single designated thread per group; barrier redistributes).
__device__ __forceinline__ void wait_ge(int* p, int v) {
  for (int it = 0; it < SPIN_LIMIT && afl_load(p) < v; ++it)
    __builtin_amdgcn_s_sleep(1);
}

// ---- prep: pack weights into frag order (bf16), combine biases, zero flags ----
__global__ void prep_kernel(const float* __restrict__ wih0, const float* __restrict__ whh0,
                            const float* __restrict__ bih0, const float* __restrict__ bhh0,
                            const float* __restrict__ wih1, const float* __restrict__ whh1,
                            const float* __restrict__ bih1, const float* __restrict__ bhh1,
                            const float* __restrict__ wih2, const float* __restrict__ whh2,
                            const float* __restrict__ bih2, const float* __restrict__ bhh2,
                            __bf16* __restrict__ ws)
{
  const float* WHH[3] = {whh0, whh1, whh2};
  const float* WIH[3] = {wih0, wih1, wih2};
  const float* BIH[3] = {bih0, bih1, bih2};
  const float* BHH[3] = {bhh0, bhh1, bhh2};
  const int NWHH = 3 * 32 * 4 * 64;   // 24576
  const int NWIH = 2 * 32 * 4 * 64;   // 16384
  const int NW0  = 32 * 64;           // 2048
  const int NBIA = 3 * 512;           // 1536
  const int NFLG = 128;               // flags + consumed
  const int TOTAL = NWHH + NWIH + NW0 + NBIA + NFLG;
  for (int idx = blockIdx.x * blockDim.x + threadIdx.x; idx < TOTAL;
       idx += gridDim.x * blockDim.x) {
    if (idx < NWHH) {
      const int lyr = idx >> 13, rem = idx & 8191;
      const int mt = rem >> 8, kc = (rem >> 6) & 3, lane = rem & 63;
      const int row = 16 * mt + (lane & 15);
      const int k0  = kc * 32 + (lane >> 4) * 8;
      const float* src = WHH[lyr] + row * H_DIM + k0;
      __bf16* dst = ws + WS_WHH + (size_t)idx * 8;
      #pragma unroll
      for (int j = 0; j < 8; ++j) dst[j] = (__bf16)src[j];
    } else if (idx < NWHH + NWIH) {
      const int i2 = idx - NWHH;
      const int lyr = (i2 >> 13) + 1, rem = i2 & 8191;
      const int mt = rem >> 8, kc = (rem >> 6) & 3, lane = rem & 63;
      const int row = 16 * mt + (lane & 15);
      const int k0  = kc * 32 + (lane >> 4) * 8;
      const float* src = WIH[lyr] + row * H_DIM + k0;
      __bf16* dst = ws + WS_WIH12 + (size_t)i2 * 8;
      #pragma unroll
      for (int j = 0; j < 8; ++j) dst[j] = (__bf16)src[j];
    } else if (idx < NWHH + NWIH + NW0) {
      const int i3 = idx - NWHH - NWIH;
      const int mt = i3 >> 6, lane = i3 & 63;
      const int row = 16 * mt + (lane & 15);
      const int k0  = (lane >> 4) * 8;
      __bf16* dst = ws + WS_WIH0 + (size_t)i3 * 8;
      #pragma unroll
      for (int j = 0; j < 8; ++j) {
        const int k = k0 + j;
        dst[j] = (k < F_IN_D) ? (__bf16)WIH[0][row * F_IN_D + k] : (__bf16)0.f;
      }
    } else if (idx < NWHH + NWIH + NW0 + NBIA) {
      const int i4 = idx - NWHH - NWIH - NW0;
      float* fb = (float*)(ws + WS_BIAS);
      fb[i4] = BIH[i4 >> 9][i4 & 511] + BHH[i4 >> 9][i4 & 511];
    } else {
      const int i5 = idx - NWHH - NWIH - NW0 - NBIA;
      ((int*)(ws + WS_FLAGS))[i5] = 0;
    }
  }
}

// R12: R9b was LATENCY-bound (step 1.25us vs ~0.47us issue floor at 2
// waves/SIMD). Fix: fuse TWO batch groups into one 1024-thread block
// (48 blocks, 16 waves, 4 waves/SIMD) -- waves 0-7 run group 2gp, waves 8-15
// run group 2gp+1: two independent recurrence chains interleave on each SIMD,
// doubling latency hiding; per-thread code/registers unchanged. Also: h buffer
// merged into hist (step s reads B-frag from hist[s-1], s=0 from hist[TC-1]
// of the previous chunk) -- one ds_write per step, 16KB LDS saved. Per-group
// ring/flag protocol byte-identical to the passing R5..R9b lineage; both
// groups of a block share each barrier (lockstep, same layer => symmetric).
__global__ __launch_bounds__(NTHREADS, 4)
void lstm_kernel(const float* __restrict__ x,
                 const float* __restrict__ fc1w, const float* __restrict__ fc1b,
                 const float* __restrict__ fc2w, const float* __restrict__ fc2b,
                 float* __restrict__ out, __bf16* __restrict__ ws)
{
  __shared__ SharedMem sh;
  const int tid = threadIdx.x;
  const int grp = tid >> 9;          // 0/1: which batch group this thread serves
  const int t9  = tid & 511;         // thread index within the group
  const int w   = t9 >> 6;           // wave 0..7 within group
  const int l   = t9 & 63;           // lane
  const int q   = l >> 4;            // quad 0..3
  const int n16 = l & 15;            // MFMA col = batch row within group
  const int lyr = blockIdx.x >> 4;   // 0..2
  const int g   = (blockIdx.x & 15) * 2 + grp;   // batch group 0..31
  const int bg  = g * BBATCH;
  const int kg_w = 2 * w + (q >> 1); // kgroup this thread's h-rows land in
  const int sub  = (q & 1) * 4;      // sub-offset within the 8-elem kgroup

  int* flags = (int*)(ws + WS_FLAGS);
  int* cons  = flags + 64;
  const int myidx = (lyr < 2) ? lyr * NGRP + g : 0;
  const int upidx = (lyr > 0) ? (lyr - 1) * NGRP + g : 0;
  int* flag_my = &flags[myidx];
  int* flag_up = &flags[upidx];
  int* cons_my = &cons[myidx];
  int* cons_up = &cons[upidx];
  u64*       mybuf = (u64*)(ws + WS_BUF + (size_t)myidx * PAIR_ELEMS);
  const u64* upbuf = (const u64*)(ws + WS_BUF + (size_t)upidx * PAIR_ELEMS);

  // ---- resident weight fragments + bias (per-layer constants; both groups
  //      load the same layer's weights -> L1/L2 served) ----
  bf16x8 whhf[4][4];
  #pragma unroll
  for (int i = 0; i < 4; ++i)
    #pragma unroll
    for (int kc = 0; kc < 4; ++kc)
      whhf[i][kc] = *(const bf16x8*)(
          ws + WS_WHH + ((((size_t)lyr * 32 + (w + 8 * i)) * 4 + kc) * 64 + l) * 8);
  f32x4 biasv[4];
  #pragma unroll
  for (int i = 0; i < 4; ++i)
    biasv[i] = *(const f32x4*)((const float*)(ws + WS_BIAS) + lyr * 512
                               + 16 * (w + 8 * i) + 4 * q);
  bf16x8 wf[4][4];
  bf16x8 wih0f[4];
  if (lyr == 0) {
    #pragma unroll
    for (int i = 0; i < 4; ++i)
      wih0f[i] = *(const bf16x8*)(ws + WS_WIH0 + ((size_t)(w + 8 * i) * 64 + l) * 8);
  } else {
    #pragma unroll
    for (int i = 0; i < 4; ++i)
      #pragma unroll
      for (int kc = 0; kc < 4; ++kc)
        wf[i][kc] = *(const bf16x8*)(ws + WS_WIH12 +
            ((((size_t)(lyr - 1) * 32 + (w + 8 * i)) * 4 + kc) * 64 + l) * 8);
  }

  // ---- zero initial h: step 0 of chunk 0 reads hist[TC-1] ----
  {
    __bf16* hz = &sh.hist[grp][TC - 1][0][0][0];
    for (int e = t9; e < 16 * 16 * 8; e += 512) hz[e] = (__bf16)0.f;
  }
  f32x4 cst = {0.f, 0.f, 0.f, 0.f};   // cell state: rows 16w+4q+0..3, col n16
  __syncthreads();

  for (int c = 0; c < NCHUNK; ++c) {
    // ---- A) per-group waits + ONE barrier ----
    if (lyr > 0 && t9 == 0) wait_ge(flag_up, c + 1);            // upstream chunk c coherent
    if (lyr < 2 && c > RSLOT && t9 == 64) wait_ge(cons_my, c - RSLOT);  // slot for c-1 free
    __syncthreads();

    // ---- B) stage upstream slot c -> LDS ring (per group), flush hist(c-1) ----
    if (lyr > 0) {
      const u64* src = upbuf + (size_t)(c % RSLOT) * CH_U64;
      #pragma unroll
      for (int it = 0; it < 8; ++it) {
        const int j = t9 + it * 512;           // coalesced 8B x 64 lanes
        sh.ring[grp][j] = adat_load(src + j);
      }
    }
    if (lyr < 2 && c > 0) {
      u64* dst = mybuf + (size_t)((c - 1) % RSLOT) * CH_U64;
      const u64* hsrc = (const u64*)&sh.hist[grp][0][0][0][0];
      #pragma unroll
      for (int it = 0; it < 8; ++it) {
        const int j = t9 + it * 512;           // 4096 u64, verbatim copy
        adat_store(dst + j, hsrc[j]);
      }
    }

    // ---- C) barrier drains vmcnt(0)+lgkmcnt(0) for ALL threads: stage
    //         ds_writes visible, flush stores complete at IC, slot-c reads
    //         done, hist reads (flush) done before steps overwrite. ----
    __syncthreads();
    if (lyr < 2 && c > 0 && t9 == 0) afl_store(flag_my, c);
    if (lyr > 0 && t9 == 0) afl_store(cons_up, c + 1);

    // ---- steps with software-pipelined xg (liveness <= 3 entries) ----
    const __bf16* rb = (const __bf16*)sh.ring[grp];
    f32x4 xg[TC][4];

    // mini-prologue: xg[0], xg[1]
    #pragma unroll
    for (int t = 0; t < 2; ++t) {
      #pragma unroll
      for (int i = 0; i < 4; ++i) xg[t][i] = biasv[i];
      if (lyr == 0) {
        bf16x8 bfrag = zero_bf16x8();
        if (q == 0)
          bfrag = load8_f32_bf16(x + ((size_t)(bg + n16) * T_LEN + c * TC + t) * F_IN_D);
        #pragma unroll
        for (int i = 0; i < 4; ++i)
          xg[t][i] = __builtin_amdgcn_mfma_f32_16x16x32_bf16(wih0f[i], bfrag, xg[t][i], 0, 0, 0);
      } else {
        #pragma unroll
        for (int kc = 0; kc < 4; ++kc) {
          const bf16x8 bfrag =
              *(const bf16x8*)&rb[((t * 16 + kc * 4 + q) * 16 + n16) * 8];
          #pragma unroll
          for (int i = 0; i < 4; ++i)
            xg[t][i] = __builtin_amdgcn_mfma_f32_16x16x32_bf16(wf[i][kc], bfrag, xg[t][i], 0, 0, 0);
        }
      }
    }

    #pragma unroll
    for (int s = 0; s < TC; ++s) {
      const int rd = (s == 0) ? TC - 1 : s - 1;   // B-frag source slice
      // recurrence MFMAs (serial chain)
      f32x4 acc[4];
      #pragma unroll
      for (int k = 0; k < 4; ++k) acc[k] = xg[s][k];
      #pragma unroll
      for (int kc = 0; kc < 4; ++kc) {
        // contiguous 1KB wave read: lane (q,n16) -> hist[rd][kc*4+q][n16][0..8)
        const bf16x8 bfrag = *(const bf16x8*)&sh.hist[grp][rd][kc * 4 + q][n16][0];
        #pragma unroll
        for (int k = 0; k < 4; ++k)
          acc[k] = __builtin_amdgcn_mfma_f32_16x16x32_bf16(whhf[k][kc], bfrag, acc[k], 0, 0, 0);
      }
      // pipelined xg(s+2): independent of acc; fills matrix-pipe slack
      if (s < TC - 2) {
        const int t = s + 2;
        #pragma unroll
        for (int i = 0; i < 4; ++i) xg[t][i] = biasv[i];
        if (lyr == 0) {
          bf16x8 bfrag = zero_bf16x8();
          if (q == 0)
            bfrag = load8_f32_bf16(x + ((size_t)(bg + n16) * T_LEN + c * TC + t) * F_IN_D);
          #pragma unroll
          for (int i = 0; i < 4; ++i)
            xg[t][i] = __builtin_amdgcn_mfma_f32_16x16x32_bf16(wih0f[i], bfrag, xg[t][i], 0, 0, 0);
        } else {
          #pragma unroll
          for (int kc = 0; kc < 4; ++kc) {
            const bf16x8 bfrag =
                *(const bf16x8*)&rb[((t * 16 + kc * 4 + q) * 16 + n16) * 8];
            #pragma unroll
            for (int i = 0; i < 4; ++i)
              xg[t][i] = __builtin_amdgcn_mfma_f32_16x16x32_bf16(wf[i][kc], bfrag, xg[t][i], 0, 0, 0);
          }
        }
      }
      // in-register gates: acc[0..3][r] = i,f,g,o for j=16w+4q+r, batch n16
      bf16x4 hb;
      #pragma unroll
      for (int r = 0; r < 4; ++r) {
        cst[r] = sigf(acc[1][r]) * cst[r] + sigmul(acc[0][r], acc[2][r]);
        hb[r]  = (__bf16)sigmul(acc[3][r], cst[r]);
      }
      *(bf16x4*)&sh.hist[grp][s][kg_w][n16][sub] = hb;   // the ONLY h write
      __syncthreads();
    }
  }

  // ---- final flush of hist(NCHUNK-1) + terminal flag ----
  if (lyr < 2) {
    const int m = NCHUNK - 1;
    if (t9 == 0) wait_ge(cons_my, m - RSLOT + 1);
    __syncthreads();
    u64* dst = mybuf + (size_t)(m % RSLOT) * CH_U64;
    const u64* hsrc = (const u64*)&sh.hist[grp][0][0][0][0];
    #pragma unroll
    for (int it = 0; it < 8; ++it) {
      const int j = t9 + it * 512;
      adat_store(dst + j, hsrc[j]);
    }
    __syncthreads();   // drains vmcnt(0): data at IC before flag
    if (t9 == 0) afl_store(flag_my, NCHUNK);
  }

  // ---- FC head: layer-2 blocks; final h = hist[TC-1] (t=511) ----
  if (lyr == 2) {
    float* zp = (float*)&sh.ring[grp][0];   // ring dead after the loop; 8KB used
    for (int j = t9; j < BBATCH * H_DIM; j += 512) {
      const int b = j >> 7, i = j & 127;
      float a = fc1b[i];
      #pragma unroll 8
      for (int k = 0; k < H_DIM; ++k)
        a += (float)sh.hist[grp][TC - 1][k >> 3][b][k & 7] * fc1w[i * H_DIM + k];
      zp[j] = fmaxf(a, 0.f);
    }
    __syncthreads();
    if (t9 < BBATCH * OUT_DIM) {
      const int b = t9 / OUT_DIM, o = t9 % OUT_DIM;
      float a = fc2b[o];
      for (int k = 0; k < H_DIM; ++k)
        a += zp[b * H_DIM + k] * fc2w[o * H_DIM + k];
      out[(size_t)(bg + b) * OUT_DIM + o] = a;
    }
  }
}

extern "C" void kernel_launch(void* const* d_in, const int* in_sizes, int n_in,
                              void* d_out, int out_size, void* d_ws, size_t ws_size,
                              hipStream_t stream) {
  const float* x    = (const float*)d_in[0];
  const float* wih0 = (const float*)d_in[1];
  const float* whh0 = (const float*)d_in[2];
  const float* bih0 = (const float*)d_in[3];
  const float* bhh0 = (const float*)d_in[4];
  const float* wih1 = (const float*)d_in[5];
  const float* whh1 = (const float*)d_in[6];
  const float* bih1 = (const float*)d_in[7];
  const float* bhh1 = (const float*)d_in[8];
  const float* wih2 = (const float*)d_in[9];
  const float* whh2 = (const float*)d_in[10];
  const float* bih2 = (const float*)d_in[11];
  const float* bhh2 = (const float*)d_in[12];
  const float* fc1w = (const float*)d_in[13];
  const float* fc1b = (const float*)d_in[14];
  const float* fc2w = (const float*)d_in[15];
  const float* fc2b = (const float*)d_in[16];
  float* out  = (float*)d_out;
  __bf16* ws  = (__bf16*)d_ws;   // ~33.7 MB used (weights + flags + ring)

  prep_kernel<<<dim3(175), dim3(256), 0, stream>>>(
      wih0, whh0, bih0, bhh0, wih1, whh1, bih1, bhh1,
      wih2, whh2, bih2, bhh2, ws);
  lstm_kernel<<<dim3(3 * NGRP / 2), dim3(NTHREADS), 0, stream>>>(
      x, fc1w, fc1b, fc2w, fc2b, out, ws);
}

// Round 14
// 5774.619 us; speedup vs baseline: 1.0959x; 1.0959x over previous
//
#include <hip/hip_runtime.h>

#define B_TOT   512
#define T_LEN   512
#define F_IN_D  8
#define H_DIM   128
#define OUT_DIM 7
#define TC      8                 // timesteps per chunk
#define NCHUNK  (T_LEN / TC)      // 64
#define RSLOT   16                // ring slots per layer boundary
#define BBATCH  16                // batch rows per group (full MFMA N)
#define NGRP    (B_TOT / BBATCH)  // 32 groups
#define NTHREADS 1024             // 16 waves = 2 groups x 8 waves
#define SPIN_LIMIT (1 << 18)      // bounded waits: fail-visible, never hang

typedef __bf16 bf16x8 __attribute__((ext_vector_type(8)));
typedef __bf16 bf16x4 __attribute__((ext_vector_type(4)));
typedef float  f32x4  __attribute__((ext_vector_type(4)));
typedef unsigned long long u64;

// ---- workspace layout (bf16 element offsets) ----
#define WS_WHH   0                     // [3][32][4][64][8] = 196608
#define WS_WIH12 196608                // [2][32][4][64][8] = 131072
#define WS_WIH0  327680                // [32][64][8] = 16384 (k>=8 zero-padded)
#define WS_BIAS  344064                // float[3][512] combined b_ih+b_hh
#define WS_FLAGS 347136                // int[2][32] flags, then int[2][32] consumed
#define WS_BUF   347648                // [2][32] pair ring buffers
#define CH_ELEMS   (TC * BBATCH * H_DIM)   // 16384 bf16 per chunk (32 KB)
#define CH_U64     (CH_ELEMS / 4)          // 4096 u64 per chunk
#define PAIR_ELEMS (RSLOT * CH_ELEMS)      // 262144 (512 KiB per pair)

// hist layout [s][kgroup][batch][8]: h(t=c*TC+s) element (b, k) at
// [s][k>>3][b][k&7]. Step s reads its B-frag from hist[s-1] (s=0: hist[TC-1],
// the previous chunk's tail -- valid: flush reads complete at phase C, new
// writes happen after) -> one ds_write per step. Reads are contiguous 1KB
// wave reads, zero bank conflicts. Ring slots use the same layout.
struct __align__(16) SharedMem {
  __bf16 hist[2][TC][16][16][8];  // [grp][s][kgroup][batch][k&7]  2x32 KB
  u64    ring[2][CH_U64];         // [grp] LDS mirror of upstream   2x32 KB
};                                // 128 KB; z (FC head) aliases ring

__device__ __forceinline__ float sigf(float x) {
  return __builtin_amdgcn_rcpf(1.f + __expf(-x));
}
// sig(a) * tanh(x) with ONE rcp: (E-1) / ((1+e^-a)(E+1)), E = e^{2*clamp(x)}.
__device__ __forceinline__ float sigmul(float a, float x) {
  const float xc = fminf(fmaxf(x, -15.f), 15.f);
  const float E  = __expf(2.f * xc);
  const float F  = __expf(-a);
  return (E - 1.f) * __builtin_amdgcn_rcpf((1.f + F) * (E + 1.f));
}
__device__ __forceinline__ bf16x8 load8_f32_bf16(const float* p) {
  const f32x4 a = *(const f32x4*)p;
  const f32x4 b = *(const f32x4*)(p + 4);
  bf16x8 r;
  #pragma unroll
  for (int j = 0; j < 4; ++j) { r[j] = (__bf16)a[j]; r[4 + j] = (__bf16)b[j]; }
  return r;
}
__device__ __forceinline__ bf16x8 zero_bf16x8() {
  bf16x8 r;
  #pragma unroll
  for (int j = 0; j < 8; ++j) r[j] = (__bf16)0.f;
  return r;
}
// All cross-block traffic is agent-scope RELAXED atomics -> coherent at the
// IC by construction (no wbl2/inv cache maintenance; R6 measured win).
// Ordering: the phase-C __syncthreads drains each thread's vmcnt(0)
// (compiler-guaranteed before s_barrier), so data atomics are complete at the
// coherence point before any flag atomic issued after it.
__device__ __forceinline__ int afl_load(int* p) {
  return __hip_atomic_load(p, __ATOMIC_RELAXED, __HIP_MEMORY_SCOPE_AGENT);
}
__device__ __forceinline__ void afl_store(int* p, int v) {
  __hip_atomic_store(p, v, __ATOMIC_RELAXED, __HIP_MEMORY_SCOPE_AGENT);
}
__device__ __forceinline__ u64 adat_load(const u64* p) {
  return __hip_atomic_load(p, __ATOMIC_RELAXED, __HIP_MEMORY_SCOPE_AGENT);
}
__device__ __forceinline__ void adat_store(u64* p, u64 v) {
  __hip_atomic_store(p, v, __ATOMIC_RELAXED, __HIP_MEMORY_SCOPE_AGENT);
}
// Bounded poll (single designated thread per group; barrier redistributes).
__device__ __forceinline__ void wait_ge(int* p, int v) {
  for (int it = 0; it < SPIN_LIMIT && afl_load(p) < v; ++it)
    __builtin_amdgcn_s_sleep(1);
}

// ---- prep: pack weights into frag order (bf16), combine biases, zero flags ----
__global__ void prep_kernel(const float* __restrict__ wih0, const float* __restrict__ whh0,
                            const float* __restrict__ bih0, const float* __restrict__ bhh0,
                            const float* __restrict__ wih1, const float* __restrict__ whh1,
                            const float* __restrict__ bih1, const float* __restrict__ bhh1,
                            const float* __restrict__ wih2, const float* __restrict__ whh2,
                            const float* __restrict__ bih2, const float* __restrict__ bhh2,
                            __bf16* __restrict__ ws)
{
  const float* WHH[3] = {whh0, whh1, whh2};
  const float* WIH[3] = {wih0, wih1, wih2};
  const float* BIH[3] = {bih0, bih1, bih2};
  const float* BHH[3] = {bhh0, bhh1, bhh2};
  const int NWHH = 3 * 32 * 4 * 64;   // 24576
  const int NWIH = 2 * 32 * 4 * 64;   // 16384
  const int NW0  = 32 * 64;           // 2048
  const int NBIA = 3 * 512;           // 1536
  const int NFLG = 128;               // flags + consumed
  const int TOTAL = NWHH + NWIH + NW0 + NBIA + NFLG;
  for (int idx = blockIdx.x * blockDim.x + threadIdx.x; idx < TOTAL;
       idx += gridDim.x * blockDim.x) {
    if (idx < NWHH) {
      const int lyr = idx >> 13, rem = idx & 8191;
      const int mt = rem >> 8, kc = (rem >> 6) & 3, lane = rem & 63;
      const int row = 16 * mt + (lane & 15);
      const int k0  = kc * 32 + (lane >> 4) * 8;
      const float* src = WHH[lyr] + row * H_DIM + k0;
      __bf16* dst = ws + WS_WHH + (size_t)idx * 8;
      #pragma unroll
      for (int j = 0; j < 8; ++j) dst[j] = (__bf16)src[j];
    } else if (idx < NWHH + NWIH) {
      const int i2 = idx - NWHH;
      const int lyr = (i2 >> 13) + 1, rem = i2 & 8191;
      const int mt = rem >> 8, kc = (rem >> 6) & 3, lane = rem & 63;
      const int row = 16 * mt + (lane & 15);
      const int k0  = kc * 32 + (lane >> 4) * 8;
      const float* src = WIH[lyr] + row * H_DIM + k0;
      __bf16* dst = ws + WS_WIH12 + (size_t)i2 * 8;
      #pragma unroll
      for (int j = 0; j < 8; ++j) dst[j] = (__bf16)src[j];
    } else if (idx < NWHH + NWIH + NW0) {
      const int i3 = idx - NWHH - NWIH;
      const int mt = i3 >> 6, lane = i3 & 63;
      const int row = 16 * mt + (lane & 15);
      const int k0  = (lane >> 4) * 8;
      __bf16* dst = ws + WS_WIH0 + (size_t)i3 * 8;
      #pragma unroll
      for (int j = 0; j < 8; ++j) {
        const int k = k0 + j;
        dst[j] = (k < F_IN_D) ? (__bf16)WIH[0][row * F_IN_D + k] : (__bf16)0.f;
      }
    } else if (idx < NWHH + NWIH + NW0 + NBIA) {
      const int i4 = idx - NWHH - NWIH - NW0;
      float* fb = (float*)(ws + WS_BIAS);
      fb[i4] = BIH[i4 >> 9][i4 & 511] + BHH[i4 >> 9][i4 & 511];
    } else {
      const int i5 = idx - NWHH - NWIH - NW0 - NBIA;
      ((int*)(ws + WS_FLAGS))[i5] = 0;
    }
  }
}

// R13b (resubmit; round-13 bench was the session's 5th content-ambiguous
// container failure -- R13's wfbase indexing re-audited and verified against
// R9b's resident-load indexing). R12's fusion with the spill fixed:
// (1) __launch_bounds__(1024) single-arg -- the 16-wave block already forces
// 4 waves/SIMD, HW cap 128 VGPR (R12's explicit ",4" drove allocation to 64
// VGPR -> spill -> 8x regression); (2) wf (input-proj weights, used only in
// the OFF-chain xg computation) loaded on-use from ws (1KB contiguous wave
// loads, L1-hot, overlap MFMA) instead of 64-VGPR resident. whhf (serial
// chain) stays resident. Structure: 2 batch groups per 1024-thread block ->
// 4 waves/SIMD of independent recurrence chains (latency hiding), hist-merged
// h (one ds_write/step), per-group ring/flag protocol of the passing
// R5..R9b lineage. All spins bounded (~7ms cap): fail-visible, never hangs.
__global__ __launch_bounds__(NTHREADS)
void lstm_kernel(const float* __restrict__ x,
                 const float* __restrict__ fc1w, const float* __restrict__ fc1b,
                 const float* __restrict__ fc2w, const float* __restrict__ fc2b,
                 float* __restrict__ out, __bf16* __restrict__ ws)
{
  __shared__ SharedMem sh;
  const int tid = threadIdx.x;
  const int grp = tid >> 9;          // 0/1: which batch group this thread serves
  const int t9  = tid & 511;         // thread index within the group
  const int w   = t9 >> 6;           // wave 0..7 within group
  const int l   = t9 & 63;           // lane
  const int q   = l >> 4;            // quad 0..3
  const int n16 = l & 15;            // MFMA col = batch row within group
  const int lyr = blockIdx.x >> 4;   // 0..2
  const int g   = (blockIdx.x & 15) * 2 + grp;   // batch group 0..31
  const int bg  = g * BBATCH;
  const int kg_w = 2 * w + (q >> 1); // kgroup this thread's h-rows land in
  const int sub  = (q & 1) * 4;      // sub-offset within the 8-elem kgroup

  int* flags = (int*)(ws + WS_FLAGS);
  int* cons  = flags + 64;
  const int myidx = (lyr < 2) ? lyr * NGRP + g : 0;
  const int upidx = (lyr > 0) ? (lyr - 1) * NGRP + g : 0;
  int* flag_my = &flags[myidx];
  int* flag_up = &flags[upidx];
  int* cons_my = &cons[myidx];
  int* cons_up = &cons[upidx];
  u64*       mybuf = (u64*)(ws + WS_BUF + (size_t)myidx * PAIR_ELEMS);
  const u64* upbuf = (const u64*)(ws + WS_BUF + (size_t)upidx * PAIR_ELEMS);
  // wf base for on-use loads (lyr>0): frag (i,kc) at wfbase + (32i+kc)*512
  const __bf16* wfbase = ws + WS_WIH12 + ((size_t)(lyr - 1) * 32 * 4 * 64) * 8
                         + (size_t)(w * 4) * 64 * 8 + (size_t)l * 8;

  // ---- resident weight fragments + bias (serial-chain constants only) ----
  bf16x8 whhf[4][4];
  #pragma unroll
  for (int i = 0; i < 4; ++i)
    #pragma unroll
    for (int kc = 0; kc < 4; ++kc)
      whhf[i][kc] = *(const bf16x8*)(
          ws + WS_WHH + ((((size_t)lyr * 32 + (w + 8 * i)) * 4 + kc) * 64 + l) * 8);
  f32x4 biasv[4];
  #pragma unroll
  for (int i = 0; i < 4; ++i)
    biasv[i] = *(const f32x4*)((const float*)(ws + WS_BIAS) + lyr * 512
                               + 16 * (w + 8 * i) + 4 * q);
  bf16x8 wih0f[4];
  if (lyr == 0) {
    #pragma unroll
    for (int i = 0; i < 4; ++i)
      wih0f[i] = *(const bf16x8*)(ws + WS_WIH0 + ((size_t)(w + 8 * i) * 64 + l) * 8);
  }

  // ---- zero initial h: step 0 of chunk 0 reads hist[TC-1] ----
  {
    __bf16* hz = &sh.hist[grp][TC - 1][0][0][0];
    for (int e = t9; e < 16 * 16 * 8; e += 512) hz[e] = (__bf16)0.f;
  }
  f32x4 cst = {0.f, 0.f, 0.f, 0.f};   // cell state: rows 16w+4q+0..3, col n16
  __syncthreads();

  for (int c = 0; c < NCHUNK; ++c) {
    // ---- A) per-group waits + ONE barrier ----
    if (lyr > 0 && t9 == 0) wait_ge(flag_up, c + 1);            // upstream chunk c coherent
    if (lyr < 2 && c > RSLOT && t9 == 64) wait_ge(cons_my, c - RSLOT);  // slot for c-1 free
    __syncthreads();

    // ---- B) stage upstream slot c -> LDS ring (per group), flush hist(c-1) ----
    if (lyr > 0) {
      const u64* src = upbuf + (size_t)(c % RSLOT) * CH_U64;
      #pragma unroll
      for (int it = 0; it < 8; ++it) {
        const int j = t9 + it * 512;           // coalesced 8B x 64 lanes
        sh.ring[grp][j] = adat_load(src + j);
      }
    }
    if (lyr < 2 && c > 0) {
      u64* dst = mybuf + (size_t)((c - 1) % RSLOT) * CH_U64;
      const u64* hsrc = (const u64*)&sh.hist[grp][0][0][0][0];
      #pragma unroll
      for (int it = 0; it < 8; ++it) {
        const int j = t9 + it * 512;           // 4096 u64, verbatim copy
        adat_store(dst + j, hsrc[j]);
      }
    }

    // ---- C) barrier drains vmcnt(0)+lgkmcnt(0) for ALL threads: stage
    //         ds_writes visible, flush stores complete at IC, slot-c reads
    //         done, hist reads (flush) done before steps overwrite. ----
    __syncthreads();
    if (lyr < 2 && c > 0 && t9 == 0) afl_store(flag_my, c);
    if (lyr > 0 && t9 == 0) afl_store(cons_up, c + 1);

    // ---- steps with software-pipelined xg (liveness <= 3 entries) ----
    const __bf16* rb = (const __bf16*)sh.ring[grp];
    f32x4 xg[TC][4];

    // mini-prologue: xg[0], xg[1]
    #pragma unroll
    for (int t = 0; t < 2; ++t) {
      #pragma unroll
      for (int i = 0; i < 4; ++i) xg[t][i] = biasv[i];
      if (lyr == 0) {
        bf16x8 bfrag = zero_bf16x8();
        if (q == 0)
          bfrag = load8_f32_bf16(x + ((size_t)(bg + n16) * T_LEN + c * TC + t) * F_IN_D);
        #pragma unroll
        for (int i = 0; i < 4; ++i)
          xg[t][i] = __builtin_amdgcn_mfma_f32_16x16x32_bf16(wih0f[i], bfrag, xg[t][i], 0, 0, 0);
      } else {
        #pragma unroll
        for (int kc = 0; kc < 4; ++kc) {
          const bf16x8 bfrag =
              *(const bf16x8*)&rb[((t * 16 + kc * 4 + q) * 16 + n16) * 8];
          #pragma unroll
          for (int i = 0; i < 4; ++i) {
            const bf16x8 wfv = *(const bf16x8*)(wfbase + ((size_t)(i * 8 * 4 + kc)) * 64 * 8);
            xg[t][i] = __builtin_amdgcn_mfma_f32_16x16x32_bf16(wfv, bfrag, xg[t][i], 0, 0, 0);
          }
        }
      }
    }

    #pragma unroll
    for (int s = 0; s < TC; ++s) {
      const int rd = (s == 0) ? TC - 1 : s - 1;   // B-frag source slice
      // recurrence MFMAs (serial chain)
      f32x4 acc[4];
      #pragma unroll
      for (int k = 0; k < 4; ++k) acc[k] = xg[s][k];
      #pragma unroll
      for (int kc = 0; kc < 4; ++kc) {
        // contiguous 1KB wave read: lane (q,n16) -> hist[rd][kc*4+q][n16][0..8)
        const bf16x8 bfrag = *(const bf16x8*)&sh.hist[grp][rd][kc * 4 + q][n16][0];
        #pragma unroll
        for (int k = 0; k < 4; ++k)
          acc[k] = __builtin_amdgcn_mfma_f32_16x16x32_bf16(whhf[k][kc], bfrag, acc[k], 0, 0, 0);
      }
      // pipelined xg(s+2): independent of acc; fills matrix-pipe slack
      if (s < TC - 2) {
        const int t = s + 2;
        #pragma unroll
        for (int i = 0; i < 4; ++i) xg[t][i] = biasv[i];
        if (lyr == 0) {
          bf16x8 bfrag = zero_bf16x8();
          if (q == 0)
            bfrag = load8_f32_bf16(x + ((size_t)(bg + n16) * T_LEN + c * TC + t) * F_IN_D);
          #pragma unroll
          for (int i = 0; i < 4; ++i)
            xg[t][i] = __builtin_amdgcn_mfma_f32_16x16x32_bf16(wih0f[i], bfrag, xg[t][i], 0, 0, 0);
        } else {
          #pragma unroll
          for (int kc = 0; kc < 4; ++kc) {
            const bf16x8 bfrag =
                *(const bf16x8*)&rb[((t * 16 + kc * 4 + q) * 16 + n16) * 8];
            #pragma unroll
            for (int i = 0; i < 4; ++i) {
              const bf16x8 wfv = *(const bf16x8*)(wfbase + ((size_t)(i * 8 * 4 + kc)) * 64 * 8);
              xg[t][i] = __builtin_amdgcn_mfma_f32_16x16x32_bf16(wfv, bfrag, xg[t][i], 0, 0, 0);
            }
          }
        }
      }
      // in-register gates: acc[0..3][r] = i,f,g,o for j=16w+4q+r, batch n16
      bf16x4 hb;
      #pragma unroll
      for (int r = 0; r < 4; ++r) {
        cst[r] = sigf(acc[1][r]) * cst[r] + sigmul(acc[0][r], acc[2][r]);
        hb[r]  = (__bf16)sigmul(acc[3][r], cst[r]);
      }
      *(bf16x4*)&sh.hist[grp][s][kg_w][n16][sub] = hb;   // the ONLY h write
      __syncthreads();
    }
  }

  // ---- final flush of hist(NCHUNK-1) + terminal flag ----
  if (lyr < 2) {
    const int m = NCHUNK - 1;
    if (t9 == 0) wait_ge(cons_my, m - RSLOT + 1);
    __syncthreads();
    u64* dst = mybuf + (size_t)(m % RSLOT) * CH_U64;
    const u64* hsrc = (const u64*)&sh.hist[grp][0][0][0][0];
    #pragma unroll
    for (int it = 0; it < 8; ++it) {
      const int j = t9 + it * 512;
      adat_store(dst + j, hsrc[j]);
    }
    __syncthreads();   // drains vmcnt(0): data at IC before flag
    if (t9 == 0) afl_store(flag_my, NCHUNK);
  }

  // ---- FC head: layer-2 blocks; final h = hist[TC-1] (t=511) ----
  if (lyr == 2) {
    float* zp = (float*)&sh.ring[grp][0];   // ring dead after the loop; 8KB used
    for (int j = t9; j < BBATCH * H_DIM; j += 512) {
      const int b = j >> 7, i = j & 127;
      float a = fc1b[i];
      #pragma unroll 8
      for (int k = 0; k < H_DIM; ++k)
        a += (float)sh.hist[grp][TC - 1][k >> 3][b][k & 7] * fc1w[i * H_DIM + k];
      zp[j] = fmaxf(a, 0.f);
    }
    __syncthreads();
    if (t9 < BBATCH * OUT_DIM) {
      const int b = t9 / OUT_DIM, o = t9 % OUT_DIM;
      float a = fc2b[o];
      for (int k = 0; k < H_DIM; ++k)
        a += zp[b * H_DIM + k] * fc2w[o * H_DIM + k];
      out[(size_t)(bg + b) * OUT_DIM + o] = a;
    }
  }
}

extern "C" void kernel_launch(void* const* d_in, const int* in_sizes, int n_in,
                              void* d_out, int out_size, void* d_ws, size_t ws_size,
                              hipStream_t stream) {
  const float* x    = (const float*)d_in[0];
  const float* wih0 = (const float*)d_in[1];
  const float* whh0 = (const float*)d_in[2];
  const float* bih0 = (const float*)d_in[3];
  const float* bhh0 = (const float*)d_in[4];
  const float* wih1 = (const float*)d_in[5];
  const float* whh1 = (const float*)d_in[6];
  const float* bih1 = (const float*)d_in[7];
  const float* bhh1 = (const float*)d_in[8];
  const float* wih2 = (const float*)d_in[9];
  const float* whh2 = (const float*)d_in[10];
  const float* bih2 = (const float*)d_in[11];
  const float* bhh2 = (const float*)d_in[12];
  const float* fc1w = (const float*)d_in[13];
  const float* fc1b = (const float*)d_in[14];
  const float* fc2w = (const float*)d_in[15];
  const float* fc2b = (const float*)d_in[16];
  float* out  = (float*)d_out;
  __bf16* ws  = (__bf16*)d_ws;   // ~33.7 MB used (weights + flags + ring)

  prep_kernel<<<dim3(175), dim3(256), 0, stream>>>(
      wih0, whh0, bih0, bhh0, wih1, whh1, bih1, bhh1,
      wih2, whh2, bih2, bhh2, ws);
  lstm_kernel<<<dim3(3 * NGRP / 2), dim3(NTHREADS), 0, stream>>>(
      x, fc1w, fc1b, fc2w, fc2b, out, ws);
}

// Round 15
// 833.038 us; speedup vs baseline: 7.5968x; 6.9320x over previous
//
#include <hip/hip_runtime.h>

#define B_TOT   512
#define T_LEN   512
#define F_IN_D  8
#define H_DIM   128
#define OUT_DIM 7
#define TC      16                // timesteps per chunk
#define NCHUNK  (T_LEN / TC)      // 32
#define RSLOT   8                 // ring slots per layer boundary
#define BBATCH  16                // batch rows per block (full MFMA N)
#define NGRP    (B_TOT / BBATCH)  // 32 groups
#define NTHREADS 512              // 8 waves
#define SPIN_LIMIT (1 << 18)      // bounded waits: fail-visible, never hang

typedef __bf16 bf16x8 __attribute__((ext_vector_type(8)));
typedef __bf16 bf16x4 __attribute__((ext_vector_type(4)));
typedef float  f32x4  __attribute__((ext_vector_type(4)));
typedef unsigned long long u64;

// ---- workspace layout (bf16 element offsets) ----
#define WS_WHH   0                     // [3][32][4][64][8] = 196608
#define WS_WIH12 196608                // [2][32][4][64][8] = 131072
#define WS_WIH0  327680                // [32][64][8] = 16384 (k>=8 zero-padded)
#define WS_BIAS  344064                // float[3][512] combined b_ih+b_hh
#define WS_FLAGS 347136                // int[2][32] flags, then int[2][32] consumed
#define WS_BUF   347648                // [2][32] pair ring buffers
#define CH_ELEMS   (TC * BBATCH * H_DIM)   // 32768 bf16 per chunk (64 KB)
#define CH_U64     (CH_ELEMS / 4)          // 8192 u64 per chunk
#define PAIR_ELEMS (RSLOT * CH_ELEMS)      // 262144 (512 KiB per pair, unchanged)

// hist layout [s][kgroup][batch][8]: h(t=c*TC+s) element (b, k) at
// [s][k>>3][b][k&7]. Step s reads its B-frag from hist[s-1] (s=0: hist[TC-1],
// the previous chunk's tail -- flush LDS-reads drain at the phase-C barrier,
// new writes happen after) -> ONE ds_write per step, no separate h buffer
// (hist-merge semantics numerically verified in R12's pass). Reads are
// contiguous 1KB wave reads, zero bank conflicts. Ring slots use the same
// layout: flush is a verbatim 64KB copy.
struct __align__(16) SharedMem {
  __bf16 hist[TC][16][16][8];  // [s][kgroup][batch][k&7]   64 KB
  u64    ring[CH_U64];         // LDS mirror of upstream     64 KB
};                             // 128 KB; z (FC head) aliases ring

__device__ __forceinline__ float sigf(float x) {
  return __builtin_amdgcn_rcpf(1.f + __expf(-x));
}
// sig(a) * tanh(x) with ONE rcp: (E-1) / ((1+e^-a)(E+1)), E = e^{2*clamp(x)}.
__device__ __forceinline__ float sigmul(float a, float x) {
  const float xc = fminf(fmaxf(x, -15.f), 15.f);
  const float E  = __expf(2.f * xc);
  const float F  = __expf(-a);
  return (E - 1.f) * __builtin_amdgcn_rcpf((1.f + F) * (E + 1.f));
}
__device__ __forceinline__ bf16x8 load8_f32_bf16(const float* p) {
  const f32x4 a = *(const f32x4*)p;
  const f32x4 b = *(const f32x4*)(p + 4);
  bf16x8 r;
  #pragma unroll
  for (int j = 0; j < 4; ++j) { r[j] = (__bf16)a[j]; r[4 + j] = (__bf16)b[j]; }
  return r;
}
__device__ __forceinline__ bf16x8 zero_bf16x8() {
  bf16x8 r;
  #pragma unroll
  for (int j = 0; j < 8; ++j) r[j] = (__bf16)0.f;
  return r;
}
// All cross-block traffic is agent-scope RELAXED atomics -> coherent at the
// IC by construction (no wbl2/inv cache maintenance; R6 measured win).
// Ordering: the phase-C __syncthreads drains each thread's vmcnt(0)
// (compiler-guaranteed before s_barrier), so data atomics are complete at the
// coherence point before any flag atomic issued after it.
__device__ __forceinline__ int afl_load(int* p) {
  return __hip_atomic_load(p, __ATOMIC_RELAXED, __HIP_MEMORY_SCOPE_AGENT);
}
__device__ __forceinline__ void afl_store(int* p, int v) {
  __hip_atomic_store(p, v, __ATOMIC_RELAXED, __HIP_MEMORY_SCOPE_AGENT);
}
__device__ __forceinline__ u64 adat_load(const u64* p) {
  return __hip_atomic_load(p, __ATOMIC_RELAXED, __HIP_MEMORY_SCOPE_AGENT);
}
__device__ __forceinline__ void adat_store(u64* p, u64 v) {
  __hip_atomic_store(p, v, __ATOMIC_RELAXED, __HIP_MEMORY_SCOPE_AGENT);
}
// Bounded poll (single designated thread; phase-A barrier redistributes).
__device__ __forceinline__ void wait_ge(int* p, int v) {
  for (int it = 0; it < SPIN_LIMIT && afl_load(p) < v; ++it)
    __builtin_amdgcn_s_sleep(1);
}

// ---- prep: pack weights into frag order (bf16), combine biases, zero flags ----
__global__ void prep_kernel(const float* __restrict__ wih0, const float* __restrict__ whh0,
                            const float* __restrict__ bih0, const float* __restrict__ bhh0,
                            const float* __restrict__ wih1, const float* __restrict__ whh1,
                            const float* __restrict__ bih1, const float* __restrict__ bhh1,
                            const float* __restrict__ wih2, const float* __restrict__ whh2,
                            const float* __restrict__ bih2, const float* __restrict__ bhh2,
                            __bf16* __restrict__ ws)
{
  const float* WHH[3] = {whh0, whh1, whh2};
  const float* WIH[3] = {wih0, wih1, wih2};
  const float* BIH[3] = {bih0, bih1, bih2};
  const float* BHH[3] = {bhh0, bhh1, bhh2};
  const int NWHH = 3 * 32 * 4 * 64;   // 24576
  const int NWIH = 2 * 32 * 4 * 64;   // 16384
  const int NW0  = 32 * 64;           // 2048
  const int NBIA = 3 * 512;           // 1536
  const int NFLG = 128;               // flags + consumed
  const int TOTAL = NWHH + NWIH + NW0 + NBIA + NFLG;
  for (int idx = blockIdx.x * blockDim.x + threadIdx.x; idx < TOTAL;
       idx += gridDim.x * blockDim.x) {
    if (idx < NWHH) {
      const int lyr = idx >> 13, rem = idx & 8191;
      const int mt = rem >> 8, kc = (rem >> 6) & 3, lane = rem & 63;
      const int row = 16 * mt + (lane & 15);
      const int k0  = kc * 32 + (lane >> 4) * 8;
      const float* src = WHH[lyr] + row * H_DIM + k0;
      __bf16* dst = ws + WS_WHH + (size_t)idx * 8;
      #pragma unroll
      for (int j = 0; j < 8; ++j) dst[j] = (__bf16)src[j];
    } else if (idx < NWHH + NWIH) {
      const int i2 = idx - NWHH;
      const int lyr = (i2 >> 13) + 1, rem = i2 & 8191;
      const int mt = rem >> 8, kc = (rem >> 6) & 3, lane = rem & 63;
      const int row = 16 * mt + (lane & 15);
      const int k0  = kc * 32 + (lane >> 4) * 8;
      const float* src = WIH[lyr] + row * H_DIM + k0;
      __bf16* dst = ws + WS_WIH12 + (size_t)i2 * 8;
      #pragma unroll
      for (int j = 0; j < 8; ++j) dst[j] = (__bf16)src[j];
    } else if (idx < NWHH + NWIH + NW0) {
      const int i3 = idx - NWHH - NWIH;
      const int mt = i3 >> 6, lane = i3 & 63;
      const int row = 16 * mt + (lane & 15);
      const int k0  = (lane >> 4) * 8;
      __bf16* dst = ws + WS_WIH0 + (size_t)i3 * 8;
      #pragma unroll
      for (int j = 0; j < 8; ++j) {
        const int k = k0 + j;
        dst[j] = (k < F_IN_D) ? (__bf16)WIH[0][row * F_IN_D + k] : (__bf16)0.f;
      }
    } else if (idx < NWHH + NWIH + NW0 + NBIA) {
      const int i4 = idx - NWHH - NWIH - NW0;
      float* fb = (float*)(ws + WS_BIAS);
      fb[i4] = BIH[i4 >> 9][i4 & 511] + BHH[i4 >> 9][i4 & 511];
    } else {
      const int i5 = idx - NWHH - NWIH - NW0 - NBIA;
      ((int*)(ws + WS_FLAGS))[i5] = 0;
    }
  }
}

// R14: fusion abandoned (hipcc pins 1024-thread blocks at 64 VGPR -> whh
// residency impossible -> unavoidable spill; R12/R13b both 7.5x regressions).
// Revert to the PROVEN R9b envelope (512 threads, 124 VGPR, 765us) plus two
// safe deltas: (1) hist-merge [numerically verified in R12's pass]: step s
// reads B-frag from hist[s-1] (s=0: hist[TC-1] = prev chunk's tail), writes
// only hist[s] -- no separate h buffer, one ds_write/step; (2) TC=16
// (32 chunks): halves per-chunk fixed cost (polls/stage/flush/C-drain/
// mini-prologue); the xg software-pipeline keeps xg liveness at ~3 entries
// independent of TC, so no R8c-style spill. RSLOT=8 keeps the ring pair at
// 512KB (PAIR_ELEMS unchanged). Sync skeleton (A/B/C phases, flags, cons,
// bounded spins) byte-identical to the passing R5..R9b lineage.
__global__ __launch_bounds__(NTHREADS, 1)
void lstm_kernel(const float* __restrict__ x,
                 const float* __restrict__ fc1w, const float* __restrict__ fc1b,
                 const float* __restrict__ fc2w, const float* __restrict__ fc2b,
                 float* __restrict__ out, __bf16* __restrict__ ws)
{
  __shared__ SharedMem sh;
  const int tid = threadIdx.x;
  const int w   = tid >> 6;   // wave 0..7
  const int l   = tid & 63;   // lane
  const int q   = l >> 4;     // quad 0..3
  const int n16 = l & 15;     // MFMA col = batch row within group
  const int lyr = blockIdx.x >> 5;   // 0..2
  const int g   = blockIdx.x & 31;   // batch group
  const int bg  = g * BBATCH;
  const int kg_w = 2 * w + (q >> 1); // kgroup this thread's h-rows land in
  const int sub  = (q & 1) * 4;      // sub-offset within the 8-elem kgroup

  int* flags = (int*)(ws + WS_FLAGS);
  int* cons  = flags + 64;
  const int myidx = (lyr < 2) ? lyr * NGRP + g : 0;
  const int upidx = (lyr > 0) ? (lyr - 1) * NGRP + g : 0;
  int* flag_my = &flags[myidx];
  int* flag_up = &flags[upidx];
  int* cons_my = &cons[myidx];
  int* cons_up = &cons[upidx];
  u64*       mybuf = (u64*)(ws + WS_BUF + (size_t)myidx * PAIR_ELEMS);
  const u64* upbuf = (const u64*)(ws + WS_BUF + (size_t)upidx * PAIR_ELEMS);

  // ---- resident weight fragments + bias (per-layer constants) ----
  bf16x8 whhf[4][4];   // recurrence weights: on the serial chain, stay resident
  #pragma unroll
  for (int i = 0; i < 4; ++i)
    #pragma unroll
    for (int kc = 0; kc < 4; ++kc)
      whhf[i][kc] = *(const bf16x8*)(
          ws + WS_WHH + ((((size_t)lyr * 32 + (w + 8 * i)) * 4 + kc) * 64 + l) * 8);
  f32x4 biasv[4];
  #pragma unroll
  for (int i = 0; i < 4; ++i)
    biasv[i] = *(const f32x4*)((const float*)(ws + WS_BIAS) + lyr * 512
                               + 16 * (w + 8 * i) + 4 * q);
  bf16x8 wf[4][4];     // input-proj weights (lyr>0 path); lyr0 uses wih0f
  bf16x8 wih0f[4];
  if (lyr == 0) {
    #pragma unroll
    for (int i = 0; i < 4; ++i)
      wih0f[i] = *(const bf16x8*)(ws + WS_WIH0 + ((size_t)(w + 8 * i) * 64 + l) * 8);
  } else {
    #pragma unroll
    for (int i = 0; i < 4; ++i)
      #pragma unroll
      for (int kc = 0; kc < 4; ++kc)
        wf[i][kc] = *(const bf16x8*)(ws + WS_WIH12 +
            ((((size_t)(lyr - 1) * 32 + (w + 8 * i)) * 4 + kc) * 64 + l) * 8);
  }

  // ---- zero initial h: step 0 of chunk 0 reads hist[TC-1] ----
  {
    __bf16* hz = &sh.hist[TC - 1][0][0][0];
    for (int e = tid; e < 16 * 16 * 8; e += NTHREADS) hz[e] = (__bf16)0.f;
  }
  f32x4 cst = {0.f, 0.f, 0.f, 0.f};   // cell state: rows 16w+4q+0..3, col n16
  __syncthreads();

  for (int c = 0; c < NCHUNK; ++c) {
    // ---- A) parallel waits + ONE barrier (R5..R9b-passing structure) ----
    if (lyr > 0 && tid == 0) wait_ge(flag_up, c + 1);           // upstream chunk c coherent
    if (lyr < 2 && c > RSLOT && tid == 64) wait_ge(cons_my, c - RSLOT); // slot for c-1 free
    __syncthreads();

    // ---- B) stage upstream slot c -> LDS ring (once), flush hist(c-1) ----
    if (lyr > 0) {
      const u64* src = upbuf + (size_t)(c % RSLOT) * CH_U64;
      #pragma unroll
      for (int it = 0; it < 16; ++it) {
        const int j = tid + it * NTHREADS;     // coalesced 8B x 64 lanes
        sh.ring[j] = adat_load(src + j);
      }
    }
    if (lyr < 2 && c > 0) {
      u64* dst = mybuf + (size_t)((c - 1) % RSLOT) * CH_U64;
      const u64* hsrc = (const u64*)&sh.hist[0][0][0][0];
      #pragma unroll
      for (int it = 0; it < 16; ++it) {
        const int j = tid + it * NTHREADS;     // 8192 u64, verbatim copy
        adat_store(dst + j, hsrc[j]);
      }
    }

    // ---- C) barrier drains vmcnt(0)+lgkmcnt(0) for ALL threads: stage
    //         ds_writes visible, flush stores complete at IC, slot-c reads
    //         done, hist reads (flush) done before steps overwrite. ----
    __syncthreads();
    if (lyr < 2 && c > 0 && tid == 0) afl_store(flag_my, c);
    if (lyr > 0 && tid == 0) afl_store(cons_up, c + 1);

    // ---- steps with software-pipelined xg (liveness <= 3 entries) ----
    const __bf16* rb = (const __bf16*)sh.ring;
    f32x4 xg[TC][4];

    // mini-prologue: xg[0], xg[1]
    #pragma unroll
    for (int t = 0; t < 2; ++t) {
      #pragma unroll
      for (int i = 0; i < 4; ++i) xg[t][i] = biasv[i];
      if (lyr == 0) {
        bf16x8 bfrag = zero_bf16x8();
        if (q == 0)
          bfrag = load8_f32_bf16(x + ((size_t)(bg + n16) * T_LEN + c * TC + t) * F_IN_D);
        #pragma unroll
        for (int i = 0; i < 4; ++i)
          xg[t][i] = __builtin_amdgcn_mfma_f32_16x16x32_bf16(wih0f[i], bfrag, xg[t][i], 0, 0, 0);
      } else {
        #pragma unroll
        for (int kc = 0; kc < 4; ++kc) {
          const bf16x8 bfrag =
              *(const bf16x8*)&rb[((t * 16 + kc * 4 + q) * 16 + n16) * 8];
          #pragma unroll
          for (int i = 0; i < 4; ++i)
            xg[t][i] = __builtin_amdgcn_mfma_f32_16x16x32_bf16(wf[i][kc], bfrag, xg[t][i], 0, 0, 0);
        }
      }
    }

    #pragma unroll
    for (int s = 0; s < TC; ++s) {
      const int rd = (s == 0) ? TC - 1 : s - 1;   // B-frag source slice
      // recurrence MFMAs (serial chain)
      f32x4 acc[4];
      #pragma unroll
      for (int k = 0; k < 4; ++k) acc[k] = xg[s][k];
      #pragma unroll
      for (int kc = 0; kc < 4; ++kc) {
        // contiguous 1KB wave read: lane (q,n16) -> hist[rd][kc*4+q][n16][0..8)
        const bf16x8 bfrag = *(const bf16x8*)&sh.hist[rd][kc * 4 + q][n16][0];
        #pragma unroll
        for (int k = 0; k < 4; ++k)
          acc[k] = __builtin_amdgcn_mfma_f32_16x16x32_bf16(whhf[k][kc], bfrag, acc[k], 0, 0, 0);
      }
      // pipelined xg(s+2): independent of acc; fills matrix-pipe slack
      if (s < TC - 2) {
        const int t = s + 2;
        #pragma unroll
        for (int i = 0; i < 4; ++i) xg[t][i] = biasv[i];
        if (lyr == 0) {
          bf16x8 bfrag = zero_bf16x8();
          if (q == 0)
            bfrag = load8_f32_bf16(x + ((size_t)(bg + n16) * T_LEN + c * TC + t) * F_IN_D);
          #pragma unroll
          for (int i = 0; i < 4; ++i)
            xg[t][i] = __builtin_amdgcn_mfma_f32_16x16x32_bf16(wih0f[i], bfrag, xg[t][i], 0, 0, 0);
        } else {
          #pragma unroll
          for (int kc = 0; kc < 4; ++kc) {
            const bf16x8 bfrag =
                *(const bf16x8*)&rb[((t * 16 + kc * 4 + q) * 16 + n16) * 8];
            #pragma unroll
            for (int i = 0; i < 4; ++i)
              xg[t][i] = __builtin_amdgcn_mfma_f32_16x16x32_bf16(wf[i][kc], bfrag, xg[t][i], 0, 0, 0);
          }
        }
      }
      // in-register gates: acc[0..3][r] = i,f,g,o for j=16w+4q+r, batch n16
      bf16x4 hb;
      #pragma unroll
      for (int r = 0; r < 4; ++r) {
        cst[r] = sigf(acc[1][r]) * cst[r] + sigmul(acc[0][r], acc[2][r]);
        hb[r]  = (__bf16)sigmul(acc[3][r], cst[r]);
      }
      *(bf16x4*)&sh.hist[s][kg_w][n16][sub] = hb;   // the ONLY h write
      __syncthreads();
    }
  }

  // ---- final flush of hist(NCHUNK-1) + terminal flag ----
  if (lyr < 2) {
    const int m = NCHUNK - 1;
    if (tid == 0) wait_ge(cons_my, m - RSLOT + 1);
    __syncthreads();
    u64* dst = mybuf + (size_t)(m % RSLOT) * CH_U64;
    const u64* hsrc = (const u64*)&sh.hist[0][0][0][0];
    #pragma unroll
    for (int it = 0; it < 16; ++it) {
      const int j = tid + it * NTHREADS;
      adat_store(dst + j, hsrc[j]);
    }
    __syncthreads();   // drains vmcnt(0): data at IC before flag
    if (tid == 0) afl_store(flag_my, NCHUNK);
  }

  // ---- FC head: layer-2 blocks; final h = hist[TC-1] (t=511) ----
  if (lyr == 2) {
    float* zp = (float*)&sh.ring[0];   // ring dead after the loop; 8KB used
    for (int j = tid; j < BBATCH * H_DIM; j += NTHREADS) {
      const int b = j >> 7, i = j & 127;
      float a = fc1b[i];
      #pragma unroll 8
      for (int k = 0; k < H_DIM; ++k)
        a += (float)sh.hist[TC - 1][k >> 3][b][k & 7] * fc1w[i * H_DIM + k];
      zp[j] = fmaxf(a, 0.f);
    }
    __syncthreads();
    if (tid < BBATCH * OUT_DIM) {
      const int b = tid / OUT_DIM, o = tid % OUT_DIM;
      float a = fc2b[o];
      for (int k = 0; k < H_DIM; ++k)
        a += zp[b * H_DIM + k] * fc2w[o * H_DIM + k];
      out[(size_t)(bg + b) * OUT_DIM + o] = a;
    }
  }
}

extern "C" void kernel_launch(void* const* d_in, const int* in_sizes, int n_in,
                              void* d_out, int out_size, void* d_ws, size_t ws_size,
                              hipStream_t stream) {
  const float* x    = (const float*)d_in[0];
  const float* wih0 = (const float*)d_in[1];
  const float* whh0 = (const float*)d_in[2];
  const float* bih0 = (const float*)d_in[3];
  const float* bhh0 = (const float*)d_in[4];
  const float* wih1 = (const float*)d_in[5];
  const float* whh1 = (const float*)d_in[6];
  const float* bih1 = (const float*)d_in[7];
  const float* bhh1 = (const float*)d_in[8];
  const float* wih2 = (const float*)d_in[9];
  const float* whh2 = (const float*)d_in[10];
  const float* bih2 = (const float*)d_in[11];
  const float* bhh2 = (const float*)d_in[12];
  const float* fc1w = (const float*)d_in[13];
  const float* fc1b = (const float*)d_in[14];
  const float* fc2w = (const float*)d_in[15];
  const float* fc2b = (const float*)d_in[16];
  float* out  = (float*)d_out;
  __bf16* ws  = (__bf16*)d_ws;   // ~33.7 MB used (weights + flags + ring)

  prep_kernel<<<dim3(175), dim3(256), 0, stream>>>(
      wih0, whh0, bih0, bhh0, wih1, whh1, bih1, bhh1,
      wih2, whh2, bih2, bhh2, ws);
  lstm_kernel<<<dim3(3 * NGRP), dim3(NTHREADS), 0, stream>>>(
      x, fc1w, fc1b, fc2w, fc2b, out, ws);
}

// Round 16
// 827.579 us; speedup vs baseline: 7.6470x; 1.0066x over previous
//
#include <hip/hip_runtime.h>

#define B_TOT   512
#define T_LEN   512
#define F_IN_D  8
#define H_DIM   128
#define OUT_DIM 7
#define TC      8                 // timesteps per chunk
#define NCHUNK  (T_LEN / TC)      // 64
#define RSLOT   16                // ring slots per layer boundary
#define BBATCH  16                // batch rows per block (full MFMA N)
#define NGRP    (B_TOT / BBATCH)  // 32 groups
#define NTHREADS 512              // 8 waves
#define SPIN_LIMIT (1 << 18)      // bounded waits: fail-visible, never hang

typedef __bf16 bf16x8 __attribute__((ext_vector_type(8)));
typedef __bf16 bf16x4 __attribute__((ext_vector_type(4)));
typedef float  f32x4  __attribute__((ext_vector_type(4)));
typedef unsigned long long u64;

// ---- workspace layout (bf16 element offsets) ----
#define WS_WHH   0                     // [3][32][4][64][8] = 196608
#define WS_WIH12 196608                // [2][32][4][64][8] = 131072
#define WS_WIH0  327680                // [32][64][8] = 16384 (k>=8 zero-padded)
#define WS_BIAS  344064                // float[3][512] combined b_ih+b_hh
#define WS_FLAGS 347136                // int[2][32] flags, then int[2][32] consumed
#define WS_BUF   347648                // [2][32] pair ring buffers
#define CH_ELEMS   (TC * BBATCH * H_DIM)   // 16384 bf16 per chunk (32 KB)
#define CH_U64     (CH_ELEMS / 4)          // 4096 u64 per chunk
#define PAIR_ELEMS (RSLOT * CH_ELEMS)      // 262144 (512 KiB per pair)

// hist layout [s][kgroup][batch][8]: h(t=c*TC+s) element (b, k) at
// [s][k>>3][b][k&7]. Step s reads its B-frag from hist[s-1] (s=0: hist[TC-1],
// the previous chunk's tail -- flush LDS-reads drain at the phase-C barrier,
// new writes happen after) -> ONE ds_write per step, no separate h buffer.
// Reads are contiguous 1KB wave reads, zero bank conflicts. Ring slots use
// the same layout: flush is a verbatim 32KB copy.
struct __align__(16) SharedMem {
  __bf16 hist[TC][16][16][8];  // [s][kgroup][batch][k&7]   32 KB
  u64    ring[CH_U64];         // LDS mirror of upstream     32 KB
};                             // 64 KB; z (FC head) aliases ring

__device__ __forceinline__ bf16x8 load8_f32_bf16(const float* p) {
  const f32x4 a = *(const f32x4*)p;
  const f32x4 b = *(const f32x4*)(p + 4);
  bf16x8 r;
  #pragma unroll
  for (int j = 0; j < 4; ++j) { r[j] = (__bf16)a[j]; r[4 + j] = (__bf16)b[j]; }
  return r;
}
__device__ __forceinline__ bf16x8 zero_bf16x8() {
  bf16x8 r;
  #pragma unroll
  for (int j = 0; j < 8; ++j) r[j] = (__bf16)0.f;
  return r;
}
// All cross-block traffic is agent-scope RELAXED atomics -> coherent at the
// IC by construction (no wbl2/inv cache maintenance; R6 measured win).
// Ordering: the phase-C __syncthreads drains each thread's vmcnt(0)
// (compiler-guaranteed before s_barrier), so data atomics are complete at the
// coherence point before any flag atomic issued after it.
__device__ __forceinline__ int afl_load(int* p) {
  return __hip_atomic_load(p, __ATOMIC_RELAXED, __HIP_MEMORY_SCOPE_AGENT);
}
__device__ __forceinline__ void afl_store(int* p, int v) {
  __hip_atomic_store(p, v, __ATOMIC_RELAXED, __HIP_MEMORY_SCOPE_AGENT);
}
__device__ __forceinline__ u64 adat_load(const u64* p) {
  return __hip_atomic_load(p, __ATOMIC_RELAXED, __HIP_MEMORY_SCOPE_AGENT);
}
__device__ __forceinline__ void adat_store(u64* p, u64 v) {
  __hip_atomic_store(p, v, __ATOMIC_RELAXED, __HIP_MEMORY_SCOPE_AGENT);
}
// Bounded poll (single designated thread; phase-A barrier redistributes).
__device__ __forceinline__ void wait_ge(int* p, int v) {
  for (int it = 0; it < SPIN_LIMIT && afl_load(p) < v; ++it)
    __builtin_amdgcn_s_sleep(1);
}

// ---- prep: pack weights into frag order (bf16), combine biases, zero flags ----
__global__ void prep_kernel(const float* __restrict__ wih0, const float* __restrict__ whh0,
                            const float* __restrict__ bih0, const float* __restrict__ bhh0,
                            const float* __restrict__ wih1, const float* __restrict__ whh1,
                            const float* __restrict__ bih1, const float* __restrict__ bhh1,
                            const float* __restrict__ wih2, const float* __restrict__ whh2,
                            const float* __restrict__ bih2, const float* __restrict__ bhh2,
                            __bf16* __restrict__ ws)
{
  const float* WHH[3] = {whh0, whh1, whh2};
  const float* WIH[3] = {wih0, wih1, wih2};
  const float* BIH[3] = {bih0, bih1, bih2};
  const float* BHH[3] = {bhh0, bhh1, bhh2};
  const int NWHH = 3 * 32 * 4 * 64;   // 24576
  const int NWIH = 2 * 32 * 4 * 64;   // 16384
  const int NW0  = 32 * 64;           // 2048
  const int NBIA = 3 * 512;           // 1536
  const int NFLG = 128;               // flags + consumed
  const int TOTAL = NWHH + NWIH + NW0 + NBIA + NFLG;
  for (int idx = blockIdx.x * blockDim.x + threadIdx.x; idx < TOTAL;
       idx += gridDim.x * blockDim.x) {
    if (idx < NWHH) {
      const int lyr = idx >> 13, rem = idx & 8191;
      const int mt = rem >> 8, kc = (rem >> 6) & 3, lane = rem & 63;
      const int row = 16 * mt + (lane & 15);
      const int k0  = kc * 32 + (lane >> 4) * 8;
      const float* src = WHH[lyr] + row * H_DIM + k0;
      __bf16* dst = ws + WS_WHH + (size_t)idx * 8;
      #pragma unroll
      for (int j = 0; j < 8; ++j) dst[j] = (__bf16)src[j];
    } else if (idx < NWHH + NWIH) {
      const int i2 = idx - NWHH;
      const int lyr = (i2 >> 13) + 1, rem = i2 & 8191;
      const int mt = rem >> 8, kc = (rem >> 6) & 3, lane = rem & 63;
      const int row = 16 * mt + (lane & 15);
      const int k0  = kc * 32 + (lane >> 4) * 8;
      const float* src = WIH[lyr] + row * H_DIM + k0;
      __bf16* dst = ws + WS_WIH12 + (size_t)i2 * 8;
      #pragma unroll
      for (int j = 0; j < 8; ++j) dst[j] = (__bf16)src[j];
    } else if (idx < NWHH + NWIH + NW0) {
      const int i3 = idx - NWHH - NWIH;
      const int mt = i3 >> 6, lane = i3 & 63;
      const int row = 16 * mt + (lane & 15);
      const int k0  = (lane >> 4) * 8;
      __bf16* dst = ws + WS_WIH0 + (size_t)i3 * 8;
      #pragma unroll
      for (int j = 0; j < 8; ++j) {
        const int k = k0 + j;
        dst[j] = (k < F_IN_D) ? (__bf16)WIH[0][row * F_IN_D + k] : (__bf16)0.f;
      }
    } else if (idx < NWHH + NWIH + NW0 + NBIA) {
      const int i4 = idx - NWHH - NWIH - NW0;
      float* fb = (float*)(ws + WS_BIAS);
      fb[i4] = BIH[i4 >> 9][i4 & 511] + BHH[i4 >> 9][i4 & 511];
    } else {
      const int i5 = idx - NWHH - NWIH - NW0 - NBIA;
      ((int*)(ws + WS_FLAGS))[i5] = 0;
    }
  }
}

// R15: back to TC=8 (R14's TC=16 was flat: stage/flush cost is proportional
// to TC, not fixed -- only polls/prologue amortize, and fill grows), keep
// hist-merge (one ds_write/step, 64KB LDS), and cut gate transcendentals
// 8 -> 7 per element via a merged-denominator c-update:
//   sig(f)*c + sig(i)*tanh(g) = [c(1+I)(E+1) + (E-1)(1+F)] / [(1+F)(1+I)(E+1)]
// with F=e^-f, I=e^-i, E=e^2g -- 3 exp + ONE rcp (was 2 rcp). The trans pipe
// (quarter-rate, ~512-1024 cy/SIMD/step, ON the serial chain) is the largest
// modeled step cost; exp(-o) is independent and issues early. Sync skeleton
// byte-identical to the passing R5..R14 lineage. All spins bounded.
__global__ __launch_bounds__(NTHREADS, 1)
void lstm_kernel(const float* __restrict__ x,
                 const float* __restrict__ fc1w, const float* __restrict__ fc1b,
                 const float* __restrict__ fc2w, const float* __restrict__ fc2b,
                 float* __restrict__ out, __bf16* __restrict__ ws)
{
  __shared__ SharedMem sh;
  const int tid = threadIdx.x;
  const int w   = tid >> 6;   // wave 0..7
  const int l   = tid & 63;   // lane
  const int q   = l >> 4;     // quad 0..3
  const int n16 = l & 15;     // MFMA col = batch row within group
  const int lyr = blockIdx.x >> 5;   // 0..2
  const int g   = blockIdx.x & 31;   // batch group
  const int bg  = g * BBATCH;
  const int kg_w = 2 * w + (q >> 1); // kgroup this thread's h-rows land in
  const int sub  = (q & 1) * 4;      // sub-offset within the 8-elem kgroup

  int* flags = (int*)(ws + WS_FLAGS);
  int* cons  = flags + 64;
  const int myidx = (lyr < 2) ? lyr * NGRP + g : 0;
  const int upidx = (lyr > 0) ? (lyr - 1) * NGRP + g : 0;
  int* flag_my = &flags[myidx];
  int* flag_up = &flags[upidx];
  int* cons_my = &cons[myidx];
  int* cons_up = &cons[upidx];
  u64*       mybuf = (u64*)(ws + WS_BUF + (size_t)myidx * PAIR_ELEMS);
  const u64* upbuf = (const u64*)(ws + WS_BUF + (size_t)upidx * PAIR_ELEMS);

  // ---- resident weight fragments + bias (per-layer constants) ----
  bf16x8 whhf[4][4];   // recurrence weights: on the serial chain, stay resident
  #pragma unroll
  for (int i = 0; i < 4; ++i)
    #pragma unroll
    for (int kc = 0; kc < 4; ++kc)
      whhf[i][kc] = *(const bf16x8*)(
          ws + WS_WHH + ((((size_t)lyr * 32 + (w + 8 * i)) * 4 + kc) * 64 + l) * 8);
  f32x4 biasv[4];
  #pragma unroll
  for (int i = 0; i < 4; ++i)
    biasv[i] = *(const f32x4*)((const float*)(ws + WS_BIAS) + lyr * 512
                               + 16 * (w + 8 * i) + 4 * q);
  bf16x8 wf[4][4];     // input-proj weights (lyr>0 path); lyr0 uses wih0f
  bf16x8 wih0f[4];
  if (lyr == 0) {
    #pragma unroll
    for (int i = 0; i < 4; ++i)
      wih0f[i] = *(const bf16x8*)(ws + WS_WIH0 + ((size_t)(w + 8 * i) * 64 + l) * 8);
  } else {
    #pragma unroll
    for (int i = 0; i < 4; ++i)
      #pragma unroll
      for (int kc = 0; kc < 4; ++kc)
        wf[i][kc] = *(const bf16x8*)(ws + WS_WIH12 +
            ((((size_t)(lyr - 1) * 32 + (w + 8 * i)) * 4 + kc) * 64 + l) * 8);
  }

  // ---- zero initial h: step 0 of chunk 0 reads hist[TC-1] ----
  {
    __bf16* hz = &sh.hist[TC - 1][0][0][0];
    for (int e = tid; e < 16 * 16 * 8; e += NTHREADS) hz[e] = (__bf16)0.f;
  }
  f32x4 cst = {0.f, 0.f, 0.f, 0.f};   // cell state: rows 16w+4q+0..3, col n16
  __syncthreads();

  for (int c = 0; c < NCHUNK; ++c) {
    // ---- A) parallel waits + ONE barrier (R5..R14-passing structure) ----
    if (lyr > 0 && tid == 0) wait_ge(flag_up, c + 1);           // upstream chunk c coherent
    if (lyr < 2 && c > RSLOT && tid == 64) wait_ge(cons_my, c - RSLOT); // slot for c-1 free
    __syncthreads();

    // ---- B) stage upstream slot c -> LDS ring (once), flush hist(c-1) ----
    if (lyr > 0) {
      const u64* src = upbuf + (size_t)(c % RSLOT) * CH_U64;
      #pragma unroll
      for (int it = 0; it < 8; ++it) {
        const int j = tid + it * NTHREADS;     // coalesced 8B x 64 lanes
        sh.ring[j] = adat_load(src + j);
      }
    }
    if (lyr < 2 && c > 0) {
      u64* dst = mybuf + (size_t)((c - 1) % RSLOT) * CH_U64;
      const u64* hsrc = (const u64*)&sh.hist[0][0][0][0];
      #pragma unroll
      for (int it = 0; it < 8; ++it) {
        const int j = tid + it * NTHREADS;     // 4096 u64, verbatim copy
        adat_store(dst + j, hsrc[j]);
      }
    }

    // ---- C) barrier drains vmcnt(0)+lgkmcnt(0) for ALL threads: stage
    //         ds_writes visible, flush stores complete at IC, slot-c reads
    //         done, hist reads (flush) done before steps overwrite. ----
    __syncthreads();
    if (lyr < 2 && c > 0 && tid == 0) afl_store(flag_my, c);
    if (lyr > 0 && tid == 0) afl_store(cons_up, c + 1);

    // ---- steps with software-pipelined xg (liveness <= 3 entries) ----
    const __bf16* rb = (const __bf16*)sh.ring;
    f32x4 xg[TC][4];

    // mini-prologue: xg[0], xg[1]
    #pragma unroll
    for (int t = 0; t < 2; ++t) {
      #pragma unroll
      for (int i = 0; i < 4; ++i) xg[t][i] = biasv[i];
      if (lyr == 0) {
        bf16x8 bfrag = zero_bf16x8();
        if (q == 0)
          bfrag = load8_f32_bf16(x + ((size_t)(bg + n16) * T_LEN + c * TC + t) * F_IN_D);
        #pragma unroll
        for (int i = 0; i < 4; ++i)
          xg[t][i] = __builtin_amdgcn_mfma_f32_16x16x32_bf16(wih0f[i], bfrag, xg[t][i], 0, 0, 0);
      } else {
        #pragma unroll
        for (int kc = 0; kc < 4; ++kc) {
          const bf16x8 bfrag =
              *(const bf16x8*)&rb[((t * 16 + kc * 4 + q) * 16 + n16) * 8];
          #pragma unroll
          for (int i = 0; i < 4; ++i)
            xg[t][i] = __builtin_amdgcn_mfma_f32_16x16x32_bf16(wf[i][kc], bfrag, xg[t][i], 0, 0, 0);
        }
      }
    }

    #pragma unroll
    for (int s = 0; s < TC; ++s) {
      const int rd = (s == 0) ? TC - 1 : s - 1;   // B-frag source slice
      // recurrence MFMAs (serial chain)
      f32x4 acc[4];
      #pragma unroll
      for (int k = 0; k < 4; ++k) acc[k] = xg[s][k];
      #pragma unroll
      for (int kc = 0; kc < 4; ++kc) {
        // contiguous 1KB wave read: lane (q,n16) -> hist[rd][kc*4+q][n16][0..8)
        const bf16x8 bfrag = *(const bf16x8*)&sh.hist[rd][kc * 4 + q][n16][0];
        #pragma unroll
        for (int k = 0; k < 4; ++k)
          acc[k] = __builtin_amdgcn_mfma_f32_16x16x32_bf16(whhf[k][kc], bfrag, acc[k], 0, 0, 0);
      }
      // pipelined xg(s+2): independent of acc; fills matrix-pipe slack
      if (s < TC - 2) {
        const int t = s + 2;
        #pragma unroll
        for (int i = 0; i < 4; ++i) xg[t][i] = biasv[i];
        if (lyr == 0) {
          bf16x8 bfrag = zero_bf16x8();
          if (q == 0)
            bfrag = load8_f32_bf16(x + ((size_t)(bg + n16) * T_LEN + c * TC + t) * F_IN_D);
          #pragma unroll
          for (int i = 0; i < 4; ++i)
            xg[t][i] = __builtin_amdgcn_mfma_f32_16x16x32_bf16(wih0f[i], bfrag, xg[t][i], 0, 0, 0);
        } else {
          #pragma unroll
          for (int kc = 0; kc < 4; ++kc) {
            const bf16x8 bfrag =
                *(const bf16x8*)&rb[((t * 16 + kc * 4 + q) * 16 + n16) * 8];
            #pragma unroll
            for (int i = 0; i < 4; ++i)
              xg[t][i] = __builtin_amdgcn_mfma_f32_16x16x32_bf16(wf[i][kc], bfrag, xg[t][i], 0, 0, 0);
          }
        }
      }
      // in-register gates: acc[0..3][r] = i,f,g,o for j=16w+4q+r, batch n16.
      // Merged-denominator c-update (7 trans/elem: 5 exp + 2 rcp):
      //   c' = [c(1+I)(E+1) + (E-1)(1+F)] / [(1+F)(1+I)(E+1)]
      //   h  = (Ec-1) / [(1+O)(Ec+1)],  Ec = e^{2 clamp(c')}
      bf16x4 hb;
      #pragma unroll
      for (int r = 0; r < 4; ++r) {
        const float O  = __expf(-acc[3][r]);    // independent: issue early
        const float F  = __expf(-acc[1][r]);
        const float I  = __expf(-acc[0][r]);
        const float gc = fminf(fmaxf(acc[2][r], -15.f), 15.f);
        const float E  = __expf(2.f * gc);
        const float pF = 1.f + F, pI = 1.f + I, pE = E + 1.f;
        const float piE = pI * pE;
        const float num = cst[r] * piE + (E - 1.f) * pF;
        cst[r] = num * __builtin_amdgcn_rcpf(pF * piE);
        const float cc = fminf(fmaxf(cst[r], -15.f), 15.f);
        const float Ec = __expf(2.f * cc);
        hb[r] = (__bf16)((Ec - 1.f) * __builtin_amdgcn_rcpf((1.f + O) * (Ec + 1.f)));
      }
      *(bf16x4*)&sh.hist[s][kg_w][n16][sub] = hb;   // the ONLY h write
      __syncthreads();
    }
  }

  // ---- final flush of hist(NCHUNK-1) + terminal flag ----
  if (lyr < 2) {
    const int m = NCHUNK - 1;
    if (tid == 0) wait_ge(cons_my, m - RSLOT + 1);
    __syncthreads();
    u64* dst = mybuf + (size_t)(m % RSLOT) * CH_U64;
    const u64* hsrc = (const u64*)&sh.hist[0][0][0][0];
    #pragma unroll
    for (int it = 0; it < 8; ++it) {
      const int j = tid + it * NTHREADS;
      adat_store(dst + j, hsrc[j]);
    }
    __syncthreads();   // drains vmcnt(0): data at IC before flag
    if (tid == 0) afl_store(flag_my, NCHUNK);
  }

  // ---- FC head: layer-2 blocks; final h = hist[TC-1] (t=511) ----
  if (lyr == 2) {
    float* zp = (float*)&sh.ring[0];   // ring dead after the loop; 8KB used
    for (int j = tid; j < BBATCH * H_DIM; j += NTHREADS) {
      const int b = j >> 7, i = j & 127;
      float a = fc1b[i];
      #pragma unroll 8
      for (int k = 0; k < H_DIM; ++k)
        a += (float)sh.hist[TC - 1][k >> 3][b][k & 7] * fc1w[i * H_DIM + k];
      zp[j] = fmaxf(a, 0.f);
    }
    __syncthreads();
    if (tid < BBATCH * OUT_DIM) {
      const int b = tid / OUT_DIM, o = tid % OUT_DIM;
      float a = fc2b[o];
      for (int k = 0; k < H_DIM; ++k)
        a += zp[b * H_DIM + k] * fc2w[o * H_DIM + k];
      out[(size_t)(bg + b) * OUT_DIM + o] = a;
    }
  }
}

extern "C" void kernel_launch(void* const* d_in, const int* in_sizes, int n_in,
                              void* d_out, int out_size, void* d_ws, size_t ws_size,
                              hipStream_t stream) {
  const float* x    = (const float*)d_in[0];
  const float* wih0 = (const float*)d_in[1];
  const float* whh0 = (const float*)d_in[2];
  const float* bih0 = (const float*)d_in[3];
  const float* bhh0 = (const float*)d_in[4];
  const float* wih1 = (const float*)d_in[5];
  const float* whh1 = (const float*)d_in[6];
  const float* bih1 = (const float*)d_in[7];
  const float* bhh1 = (const float*)d_in[8];
  const float* wih2 = (const float*)d_in[9];
  const float* whh2 = (const float*)d_in[10];
  const float* bih2 = (const float*)d_in[11];
  const float* bhh2 = (const float*)d_in[12];
  const float* fc1w = (const float*)d_in[13];
  const float* fc1b = (const float*)d_in[14];
  const float* fc2w = (const float*)d_in[15];
  const float* fc2b = (const float*)d_in[16];
  float* out  = (float*)d_out;
  __bf16* ws  = (__bf16*)d_ws;   // ~33.7 MB used (weights + flags + ring)

  prep_kernel<<<dim3(175), dim3(256), 0, stream>>>(
      wih0, whh0, bih0, bhh0, wih1, whh1, bih1, bhh1,
      wih2, whh2, bih2, bhh2, ws);
  lstm_kernel<<<dim3(3 * NGRP), dim3(NTHREADS), 0, stream>>>(
      x, fc1w, fc1b, fc2w, fc2b, out, ws);
}